// Round 1
// baseline (378.456 us; speedup 1.0000x reference)
//
#include <hip/hip_runtime.h>
#include <hip/hip_bf16.h>

#define B_    2
#define S_    2048
#define H_    1024
#define NH_   16
#define HD_   64
#define M_TOT (B_ * S_)   // 4096
#define K_DIM 1024

typedef __attribute__((ext_vector_type(4))) float f32x4;
typedef __attribute__((ext_vector_type(8))) short bf16x8;
typedef __attribute__((ext_vector_type(4))) short short4v;

// f32 -> bf16 round-to-nearest-even (finite inputs)
__device__ inline short f2bf(float x) {
    union { float f; unsigned u; } v; v.f = x;
    unsigned r = v.u + 0x7fffu + ((v.u >> 16) & 1u);
    return (short)(r >> 16);
}

// ---------------------------------------------------------------------------
// GEMM: C[m][n] = sum_k A[m][k] * W[n][k]   (y = x @ W^T)
// MODE 0: A = f32 (hidden), write bf16 into head-layout [B,NH,S,HD]
// MODE 1: A = bf16 (attn out), write f32 row-major to d_out
// 128x128 tile, BK=32, 256 threads (4 waves, 2x2), wave tile 64x64.
// ---------------------------------------------------------------------------
template <int MODE>
__global__ __launch_bounds__(256) void gemm128(const void* __restrict__ Ap,
                                               const float* __restrict__ W,
                                               short* __restrict__ outb,
                                               float* __restrict__ outf) {
    __shared__ short Asm[128][40];   // padded stride: 80B, spreads banks
    __shared__ short Bsm[128][40];

    const int tid  = threadIdx.x;
    const int wave = tid >> 6;
    const int lane = tid & 63;
    const int wm = (wave >> 1) * 64;
    const int wn = (wave & 1) * 64;
    const int m0 = blockIdx.x * 128;
    const int n0 = blockIdx.y * 128;

    f32x4 acc[4][4] = {};

    const int cg = tid & 7;    // 4-element column group within 32
    const int r0 = tid >> 3;   // 0..31

    for (int k0 = 0; k0 < K_DIM; k0 += 32) {
        // ---- stage A (128x32) ----
        if constexpr (MODE == 0) {
            const float* A = (const float*)Ap;
#pragma unroll
            for (int p = 0; p < 4; ++p) {
                const int r = r0 + p * 32;
                const f32x4 v = *(const f32x4*)(A + (size_t)(m0 + r) * K_DIM + k0 + cg * 4);
                short4v sv;
                sv[0] = f2bf(v[0]); sv[1] = f2bf(v[1]);
                sv[2] = f2bf(v[2]); sv[3] = f2bf(v[3]);
                *(short4v*)(&Asm[r][cg * 4]) = sv;
            }
        } else {
            const short* A = (const short*)Ap;
#pragma unroll
            for (int p = 0; p < 4; ++p) {
                const int r = r0 + p * 32;
                *(short4v*)(&Asm[r][cg * 4]) =
                    *(const short4v*)(A + (size_t)(m0 + r) * K_DIM + k0 + cg * 4);
            }
        }
        // ---- stage W (128x32) ----
#pragma unroll
        for (int p = 0; p < 4; ++p) {
            const int r = r0 + p * 32;
            const f32x4 v = *(const f32x4*)(W + (size_t)(n0 + r) * K_DIM + k0 + cg * 4);
            short4v sv;
            sv[0] = f2bf(v[0]); sv[1] = f2bf(v[1]);
            sv[2] = f2bf(v[2]); sv[3] = f2bf(v[3]);
            *(short4v*)(&Bsm[r][cg * 4]) = sv;
        }
        __syncthreads();

        bf16x8 af[4], bff[4];
#pragma unroll
        for (int i = 0; i < 4; ++i)
            af[i] = *(const bf16x8*)(&Asm[wm + i * 16 + (lane & 15)][(lane >> 4) * 8]);
#pragma unroll
        for (int j = 0; j < 4; ++j)
            bff[j] = *(const bf16x8*)(&Bsm[wn + j * 16 + (lane & 15)][(lane >> 4) * 8]);
#pragma unroll
        for (int i = 0; i < 4; ++i)
#pragma unroll
            for (int j = 0; j < 4; ++j)
                acc[i][j] = __builtin_amdgcn_mfma_f32_16x16x32_bf16(af[i], bff[j], acc[i][j], 0, 0, 0);
        __syncthreads();
    }

    // ---- epilogue ----
#pragma unroll
    for (int i = 0; i < 4; ++i)
#pragma unroll
        for (int j = 0; j < 4; ++j)
#pragma unroll
            for (int r = 0; r < 4; ++r) {
                const int m = m0 + wm + i * 16 + (lane >> 4) * 4 + r;
                const int n = n0 + wn + j * 16 + (lane & 15);
                const float v = acc[i][j][r];
                if constexpr (MODE == 0) {
                    const int b = m >> 11, s = m & 2047, h = n >> 6, d = n & 63;
                    outb[(((size_t)(b * NH_ + h)) * S_ + s) * HD_ + d] = f2bf(v);
                } else {
                    outf[(size_t)m * H_ + n] = v;
                }
            }
}

// ---------------------------------------------------------------------------
// Flash attention, causal. grid = (S/64, NH, B), 256 threads (4 waves).
// Each wave owns 16 q-rows; kv-tiles of 32 keys.
// ---------------------------------------------------------------------------
__global__ __launch_bounds__(256) void flash_attn(const short* __restrict__ Qb,
                                                  const short* __restrict__ Kb,
                                                  const short* __restrict__ Vb,
                                                  short* __restrict__ Ob) {
    const int qt = blockIdx.x, h = blockIdx.y, b = blockIdx.z;
    const int tid = threadIdx.x, wave = tid >> 6, lane = tid & 63;

    const size_t headoff = ((size_t)(b * NH_ + h)) * S_ * HD_;
    const short* Q = Qb + headoff;
    const short* K = Kb + headoff;
    const short* V = Vb + headoff;

    const int q0      = qt * 64;
    const int qrow_lo = q0 + wave * 16;

    // preload Q frags (16 rows x 64 d -> 2 K-slices)
    bf16x8 qf[2];
#pragma unroll
    for (int f = 0; f < 2; ++f)
        qf[f] = *(const bf16x8*)(&Q[(size_t)(qrow_lo + (lane & 15)) * HD_ + f * 32 + (lane >> 4) * 8]);

    f32x4 o[4] = {};           // 16 q-rows x 64 d
    float mrun[4], lrun[4];
#pragma unroll
    for (int r = 0; r < 4; ++r) { mrun[r] = -1e30f; lrun[r] = 0.f; }

    __shared__ short Vt[64][40];        // V^T tile: [d][k_in_tile]
    __shared__ short Pl[4][16][40];     // per-wave P tile: [qrow][k_in_tile]

    const int nkt = q0 / 32 + 2;        // causal: keys 0 .. q0+63
    for (int kt = 0; kt < nkt; ++kt) {
        __syncthreads();                // protect previous Vt reads
        {   // cooperative V^T staging: 32 rows x 64 d
            const int r  = tid >> 3;
            const int d0 = (tid & 7) * 8;
            const bf16x8 vv = *(const bf16x8*)(&V[(size_t)(kt * 32 + r) * HD_ + d0]);
#pragma unroll
            for (int i = 0; i < 8; ++i) Vt[d0 + i][r] = vv[i];
        }
        __syncthreads();

        // scores: 16 q-rows x 32 keys (two 16-col halves)
        f32x4 s[2] = {};
#pragma unroll
        for (int t = 0; t < 2; ++t)
#pragma unroll
            for (int f = 0; f < 2; ++f) {
                const bf16x8 kf = *(const bf16x8*)(&K[(size_t)(kt * 32 + t * 16 + (lane & 15)) * HD_ +
                                                     f * 32 + (lane >> 4) * 8]);
                s[t] = __builtin_amdgcn_mfma_f32_16x16x32_bf16(qf[f], kf, s[t], 0, 0, 0);
            }

        // scale + causal mask
        const int qr = qrow_lo + ((lane >> 4) << 2);
#pragma unroll
        for (int t = 0; t < 2; ++t) {
            const int kc = kt * 32 + t * 16 + (lane & 15);
#pragma unroll
            for (int r = 0; r < 4; ++r) {
                const float v = s[t][r] * 0.125f;
                s[t][r] = (kc <= qr + r) ? v : -1e30f;
            }
        }

        // online softmax per row (row lives in 16-lane group, reg r)
#pragma unroll
        for (int r = 0; r < 4; ++r) {
            float mt = fmaxf(s[0][r], s[1][r]);
#pragma unroll
            for (int off = 1; off < 16; off <<= 1)
                mt = fmaxf(mt, __shfl_xor(mt, off, 64));
            const float mnew = fmaxf(mrun[r], mt);
            const float corr = __expf(mrun[r] - mnew);
            mrun[r] = mnew;
            const float p0 = __expf(s[0][r] - mnew);
            const float p1 = __expf(s[1][r] - mnew);
            s[0][r] = p0; s[1][r] = p1;
            float ps = p0 + p1;
#pragma unroll
            for (int off = 1; off < 16; off <<= 1)
                ps += __shfl_xor(ps, off, 64);
            lrun[r] = lrun[r] * corr + ps;
#pragma unroll
            for (int t2 = 0; t2 < 4; ++t2) o[t2][r] *= corr;
        }

        // P (D-layout) -> LDS -> A-frag layout
#pragma unroll
        for (int t = 0; t < 2; ++t)
#pragma unroll
            for (int r = 0; r < 4; ++r)
                Pl[wave][(lane >> 4) * 4 + r][t * 16 + (lane & 15)] = f2bf(s[t][r]);

        const bf16x8 pf = *(const bf16x8*)(&Pl[wave][lane & 15][(lane >> 4) * 8]);

        // O += P @ V_tile
#pragma unroll
        for (int t2 = 0; t2 < 4; ++t2) {
            const bf16x8 vf = *(const bf16x8*)(&Vt[t2 * 16 + (lane & 15)][(lane >> 4) * 8]);
            o[t2] = __builtin_amdgcn_mfma_f32_16x16x32_bf16(pf, vf, o[t2], 0, 0, 0);
        }
    }

    // epilogue: write bf16 attn output in [B*S, H] layout
#pragma unroll
    for (int t2 = 0; t2 < 4; ++t2)
#pragma unroll
        for (int r = 0; r < 4; ++r) {
            const int srow = q0 + wave * 16 + (lane >> 4) * 4 + r;
            const int col  = h * HD_ + t2 * 16 + (lane & 15);
            const float val = o[t2][r] / lrun[r];
            Ob[((size_t)(b * S_) + srow) * H_ + col] = f2bf(val);
        }
}

// ---------------------------------------------------------------------------
extern "C" void kernel_launch(void* const* d_in, const int* in_sizes, int n_in,
                              void* d_out, int out_size, void* d_ws, size_t ws_size,
                              hipStream_t stream) {
    const float* x  = (const float*)d_in[0];
    // d_in[1] = attention_mask (pure causal; computed in-kernel)
    const float* Wq = (const float*)d_in[2];
    const float* Wk = (const float*)d_in[3];
    const float* Wv = (const float*)d_in[4];
    const float* Wo = (const float*)d_in[5];
    float* out = (float*)d_out;

    short* qb = (short*)d_ws;
    short* kb = qb + (size_t)M_TOT * H_;
    short* vb = kb + (size_t)M_TOT * H_;
    short* ab = vb + (size_t)M_TOT * H_;

    const dim3 gg(M_TOT / 128, H_ / 128);
    const dim3 blk(256);

    hipLaunchKernelGGL((gemm128<0>), gg, blk, 0, stream, (const void*)x, Wq, qb, (float*)nullptr);
    hipLaunchKernelGGL((gemm128<0>), gg, blk, 0, stream, (const void*)x, Wk, kb, (float*)nullptr);
    hipLaunchKernelGGL((gemm128<0>), gg, blk, 0, stream, (const void*)x, Wv, vb, (float*)nullptr);

    flash_attn<<<dim3(S_ / 64, NH_, B_), blk, 0, stream>>>(qb, kb, vb, ab);

    hipLaunchKernelGGL((gemm128<1>), gg, blk, 0, stream, (const void*)ab, Wo, (short*)nullptr, out);
}

// Round 3
// 225.352 us; speedup vs baseline: 1.6794x; 1.6794x over previous
//
#include <hip/hip_runtime.h>
#include <hip/hip_bf16.h>

#define B_   2
#define S_   2048
#define H_   1024
#define NH_  16
#define HD_  64
#define MTOT 4096
#define KD   1024

typedef __attribute__((ext_vector_type(4)))  float    f32x4;
typedef __attribute__((ext_vector_type(16))) float    f32x16;
typedef __attribute__((ext_vector_type(8)))  short    bf16x8;
typedef __attribute__((ext_vector_type(4)))  short    bf16x4;
typedef __attribute__((ext_vector_type(4)))  unsigned u32x4;

// f32 -> bf16 RNE (scalar)
__device__ inline short f2bf(float x) {
    union { float f; unsigned u; } v; v.f = x;
    unsigned r = v.u + 0x7fffu + ((v.u >> 16) & 1u);
    return (short)(r >> 16);
}
// pack two f32 -> one u32 of 2 bf16 (RNE bit-math; trivially copyable types only)
__device__ inline unsigned pk2(float lo, float hi) {
    return (unsigned)(unsigned short)f2bf(lo) | ((unsigned)(unsigned short)f2bf(hi) << 16);
}
// async global->LDS, 16B per lane; LDS dest is wave-uniform base + lane*16
__device__ inline void gload16(const void* g, void* l) {
    __builtin_amdgcn_global_load_lds(
        (const __attribute__((address_space(1))) unsigned*)g,
        (__attribute__((address_space(3))) unsigned*)l, 16, 0, 0);
}

// ---------------------------------------------------------------------------
// x (f32) -> bf16, 8 elems/thread
// ---------------------------------------------------------------------------
__global__ __launch_bounds__(256) void cvt_x(const float* __restrict__ x,
                                             unsigned* __restrict__ xb) {
    const size_t i = ((size_t)blockIdx.x * 256 + threadIdx.x) * 8;
    const f32x4 a = *(const f32x4*)(x + i);
    const f32x4 b = *(const f32x4*)(x + i + 4);
    u32x4 p;
    p[0] = pk2(a[0], a[1]); p[1] = pk2(a[2], a[3]);
    p[2] = pk2(b[0], b[1]); p[3] = pk2(b[2], b[3]);
    *(u32x4*)(xb + i / 2) = p;
}

// ---------------------------------------------------------------------------
// GEMM  C[m][n] = sum_k A[m][k] * W[n][k]
// A: bf16 (gload_lds staged, swizzled).  W: f32 (reg-staged -> bf16 LDS).
// MODE 0: fused QKV (blockIdx.y selects weight), out bf16 head-layout.
// MODE 1: final projection, out f32 row-major.
// 128x128 tile, BK=64, 256 threads (2x2 waves, 64x64 each).
// ---------------------------------------------------------------------------
template <int MODE>
__global__ __launch_bounds__(256) void gemm_m97(const short* __restrict__ A,
                                                const float* __restrict__ W0,
                                                const float* __restrict__ W1,
                                                const float* __restrict__ W2,
                                                short* __restrict__ outb,
                                                float* __restrict__ outf) {
    __shared__ short As[128 * 64];
    __shared__ short Bs[128 * 64];

    const int tid = threadIdx.x, wave = tid >> 6, lane = tid & 63;
    const int wm = (wave >> 1) * 64, wn = (wave & 1) * 64;
    const int m0 = blockIdx.x * 128;

    int n0; const float* W; int widx = 0;
    if constexpr (MODE == 0) {
        widx = blockIdx.y >> 3;
        n0 = (blockIdx.y & 7) * 128;
        W = (widx == 0) ? W0 : (widx == 1) ? W1 : W2;
    } else {
        n0 = blockIdx.y * 128;
        W = W0;
    }

    f32x4 acc[4][4] = {};
    const int brow = tid >> 1, bkh = (tid & 1) * 32;

    for (int k0 = 0; k0 < KD; k0 += 64) {
        // ---- A tile: 128x64 bf16 via global_load_lds, pre-swizzled source ----
#pragma unroll
        for (int c = 0; c < 4; ++c) {
            const int lin = wave * 4096 + c * 1024 + lane * 16;   // byte in tile
            const int row = lin >> 7;
            const int col = (lin & 127) ^ ((row & 7) << 4);
            gload16(A + (size_t)(m0 + row) * KD + k0 + (col >> 1),
                    (char*)As + wave * 4096 + c * 1024);
        }
        // ---- B tile: f32 -> bf16 pairs, swizzled LDS write ----
        {
            const float* wsrc = W + (size_t)(n0 + brow) * KD + k0 + bkh;
            const int base = brow * 128 + bkh * 2;
            const int swz = (brow & 7) << 4;
#pragma unroll
            for (int q = 0; q < 4; ++q) {
                const f32x4 a = *(const f32x4*)(wsrc + q * 8);
                const f32x4 b = *(const f32x4*)(wsrc + q * 8 + 4);
                u32x4 p;
                p[0] = pk2(a[0], a[1]); p[1] = pk2(a[2], a[3]);
                p[2] = pk2(b[0], b[1]); p[3] = pk2(b[2], b[3]);
                *(u32x4*)((char*)Bs + ((base + q * 16) ^ swz)) = p;
            }
        }
        __syncthreads();

#pragma unroll
        for (int ks = 0; ks < 2; ++ks) {
            bf16x8 af[4], bf[4];
#pragma unroll
            for (int i = 0; i < 4; ++i) {
                const int row = wm + i * 16 + (lane & 15);
                af[i] = *(const bf16x8*)((char*)As + row * 128 +
                        ((ks * 64 + (lane >> 4) * 16) ^ ((row & 7) << 4)));
            }
#pragma unroll
            for (int j = 0; j < 4; ++j) {
                const int row = wn + j * 16 + (lane & 15);
                bf[j] = *(const bf16x8*)((char*)Bs + row * 128 +
                        ((ks * 64 + (lane >> 4) * 16) ^ ((row & 7) << 4)));
            }
#pragma unroll
            for (int i = 0; i < 4; ++i)
#pragma unroll
                for (int j = 0; j < 4; ++j)
                    acc[i][j] = __builtin_amdgcn_mfma_f32_16x16x32_bf16(af[i], bf[j], acc[i][j], 0, 0, 0);
        }
        __syncthreads();
    }

    // ---- epilogue ----
#pragma unroll
    for (int i = 0; i < 4; ++i)
#pragma unroll
        for (int j = 0; j < 4; ++j)
#pragma unroll
            for (int r = 0; r < 4; ++r) {
                const int m = m0 + wm + i * 16 + (lane >> 4) * 4 + r;
                const int n = n0 + wn + j * 16 + (lane & 15);
                const float v = acc[i][j][r];
                if constexpr (MODE == 0) {
                    const int b = m >> 11, s = m & 2047, h = n >> 6, d = n & 63;
                    outb[(size_t)widx * MTOT * H_ +
                         (((size_t)(b * NH_ + h)) * S_ + s) * HD_ + d] = f2bf(v);
                } else {
                    outf[(size_t)m * H_ + n] = v;
                }
            }
}

// ---------------------------------------------------------------------------
// Flash attention, causal, swapped-operand 32x32 MFMA.
// grid (S/128, NH, B), 256 threads = 4 waves x 32 q-rows. KV tile = 64.
// Scores: S^T = mfma(K, Q)  -> lane owns q-col (lane&31), softmax lane-local.
// PV:     O^T = mfma(V^T, P) -> same q-col ownership, rescale lane-local.
// ---------------------------------------------------------------------------
__global__ __launch_bounds__(256) void flash2(const short* __restrict__ Qb,
                                              const short* __restrict__ Kb,
                                              const short* __restrict__ Vb,
                                              short* __restrict__ Ob) {
    const int qt = blockIdx.x, h = blockIdx.y, b = blockIdx.z;
    const int tid = threadIdx.x, wave = tid >> 6, lane = tid & 63;
    const int q0 = qt * 128;
    const int qw0 = q0 + wave * 32;
    const size_t hoff = ((size_t)(b * NH_ + h)) * S_ * HD_;
    const short* Q = Qb + hoff;
    const short* K = Kb + hoff;
    const short* V = Vb + hoff;

    __shared__ short Ks[64 * 64];   // [key][d], XOR-swizzled
    __shared__ short Vt[64 * 64];   // [d][key], XOR-swizzled

    const int ql = lane & 31;       // q column owned by this lane
    const int hh = lane >> 5;

    // Q as B-frag: col=lane&31=q, k=d slice
    bf16x8 qf[4];
#pragma unroll
    for (int ds = 0; ds < 4; ++ds)
        qf[ds] = *(const bf16x8*)(Q + (size_t)(qw0 + ql) * HD_ + ds * 16 + hh * 8);

    f32x16 ot[2] = {};              // O^T accum: d tiles 0-31 / 32-63
    float mrun = -1e30f, lrun = 0.f;
    const float c2 = 0.18033688011112042f;   // 0.125 * log2(e)

    const int nkt = 2 * qt + 2;
    for (int kt = 0; kt < nkt; ++kt) {
        __syncthreads();            // protect previous tile reads
        // ---- K tile: 64x64 via gload_lds, pre-swizzled source ----
#pragma unroll
        for (int c = 0; c < 2; ++c) {
            const int lin = wave * 2048 + c * 1024 + lane * 16;
            const int row = lin >> 7;
            const int col = (lin & 127) ^ ((row & 7) << 4);
            gload16(K + (size_t)(kt * 64 + row) * HD_ + (col >> 1),
                    (char*)Ks + wave * 2048 + c * 1024);
        }
        // ---- V^T tile: transpose-stage, packed pair writes, swizzled ----
        {
            const int kk = (tid & 31) * 2, d0 = (tid >> 5) * 8;
            const bf16x8 v0 = *(const bf16x8*)(V + (size_t)(kt * 64 + kk) * HD_ + d0);
            const bf16x8 v1 = *(const bf16x8*)(V + (size_t)(kt * 64 + kk + 1) * HD_ + d0);
#pragma unroll
            for (int i = 0; i < 8; ++i) {
                const int d = d0 + i;
                const int byt = d * 128 + kk * 2;
                *(unsigned*)((char*)Vt + (byt ^ ((d & 7) << 4))) =
                    (unsigned)(unsigned short)v0[i] | ((unsigned)(unsigned short)v1[i] << 16);
            }
        }
        __syncthreads();

        if (kt * 64 <= qw0 + 31) {              // wave has unmasked keys
            const bool need_mask = (kt * 64 + 63) > qw0;

            // ---- scores S^T[key][q] ----
            f32x16 st[2] = {};
#pragma unroll
            for (int t = 0; t < 2; ++t)
#pragma unroll
                for (int ds = 0; ds < 4; ++ds) {
                    const int row = t * 32 + ql;   // key row in Ks
                    const bf16x8 kf = *(const bf16x8*)((char*)Ks + row * 128 +
                            ((ds * 32 + hh * 16) ^ ((row & 7) << 4)));
                    st[t] = __builtin_amdgcn_mfma_f32_32x32x16_bf16(kf, qf[ds], st[t], 0, 0, 0);
                }

            float sraw[32];
#pragma unroll
            for (int t = 0; t < 2; ++t)
#pragma unroll
                for (int r = 0; r < 16; ++r) {
                    float v = st[t][r];
                    if (need_mask) {
                        const int key = kt * 64 + t * 32 + (r & 3) + 8 * (r >> 2) + 4 * hh;
                        if (key > qw0 + ql) v = -1e30f;
                    }
                    sraw[t * 16 + r] = v;
                }

            // ---- lane-local softmax (tree reduce + 1 shfl) ----
            float tr[32];
#pragma unroll
            for (int i = 0; i < 32; ++i) tr[i] = sraw[i];
#pragma unroll
            for (int stp = 16; stp >= 1; stp >>= 1)
#pragma unroll
                for (int i = 0; i < 16; ++i)
                    if (i < stp) tr[i] = fmaxf(tr[i], tr[i + stp]);
            float pmax = fmaxf(tr[0], __shfl_xor(tr[0], 32, 64));
            const float mnew = fmaxf(mrun, pmax);
            const float corr = exp2f((mrun - mnew) * c2);
            mrun = mnew;
            const float mc = mnew * c2;

            float p[32];
#pragma unroll
            for (int i = 0; i < 32; ++i) p[i] = exp2f(fmaf(sraw[i], c2, -mc));
#pragma unroll
            for (int i = 0; i < 32; ++i) tr[i] = p[i];
#pragma unroll
            for (int stp = 16; stp >= 1; stp >>= 1)
#pragma unroll
                for (int i = 0; i < 16; ++i)
                    if (i < stp) tr[i] += tr[i + stp];
            const float psum = tr[0] + __shfl_xor(tr[0], 32, 64);
            lrun = lrun * corr + psum;
#pragma unroll
            for (int dt = 0; dt < 2; ++dt)
#pragma unroll
                for (int r = 0; r < 16; ++r) ot[dt][r] *= corr;

            // ---- P pack -> B-frag (4 shfl per 16-key slice), PV MFMAs ----
#pragma unroll
            for (int ks = 0; ks < 4; ++ks) {
                const int t = ks >> 1, rb = (ks & 1) * 8;
                const unsigned a0 = pk2(p[t * 16 + rb + 0], p[t * 16 + rb + 1]);
                const unsigned a1 = pk2(p[t * 16 + rb + 2], p[t * 16 + rb + 3]);
                const unsigned a2 = pk2(p[t * 16 + rb + 4], p[t * 16 + rb + 5]);
                const unsigned a3 = pk2(p[t * 16 + rb + 6], p[t * 16 + rb + 7]);
                const unsigned s0 = __shfl_xor(a0, 32, 64);
                const unsigned s1 = __shfl_xor(a1, 32, 64);
                const unsigned s2 = __shfl_xor(a2, 32, 64);
                const unsigned s3 = __shfl_xor(a3, 32, 64);
                u32x4 pw;
                pw[0] = hh ? s2 : a0;
                pw[1] = hh ? s3 : a1;
                pw[2] = hh ? a2 : s0;
                pw[3] = hh ? a3 : s1;
                const bf16x8 pf = __builtin_bit_cast(bf16x8, pw);
#pragma unroll
                for (int dt = 0; dt < 2; ++dt) {
                    const int row = dt * 32 + ql;  // d row in Vt
                    const bf16x8 vf = *(const bf16x8*)((char*)Vt + row * 128 +
                            ((ks * 32 + hh * 16) ^ ((row & 7) << 4)));
                    ot[dt] = __builtin_amdgcn_mfma_f32_32x32x16_bf16(vf, pf, ot[dt], 0, 0, 0);
                }
            }
        }
    }

    // ---- epilogue: O^T regs -> row-major bf16 [B*S][H], b64 stores ----
    const float inv = 1.f / lrun;
    short* orow = Ob + ((size_t)(b * S_) + q0 + wave * 32 + ql) * H_ + h * HD_;
#pragma unroll
    for (int dt = 0; dt < 2; ++dt)
#pragma unroll
        for (int g4 = 0; g4 < 4; ++g4) {
            const int dbase = dt * 32 + 8 * g4 + 4 * hh;
            bf16x4 w;
#pragma unroll
            for (int rr = 0; rr < 4; ++rr)
                w[rr] = f2bf(ot[dt][g4 * 4 + rr] * inv);
            *(bf16x4*)(orow + dbase) = w;
        }
}

// ---------------------------------------------------------------------------
extern "C" void kernel_launch(void* const* d_in, const int* in_sizes, int n_in,
                              void* d_out, int out_size, void* d_ws, size_t ws_size,
                              hipStream_t stream) {
    const float* x  = (const float*)d_in[0];
    const float* Wq = (const float*)d_in[2];
    const float* Wk = (const float*)d_in[3];
    const float* Wv = (const float*)d_in[4];
    const float* Wo = (const float*)d_in[5];
    float* out = (float*)d_out;

    short* qkv = (short*)d_ws;                        // 3 x 4M bf16 (24 MB)
    short* xb  = qkv + (size_t)3 * MTOT * H_;         // 4M bf16 (8 MB), reused as attn-out

    cvt_x<<<2048, 256, 0, stream>>>(x, (unsigned*)xb);

    gemm_m97<0><<<dim3(32, 24), 256, 0, stream>>>(xb, Wq, Wk, Wv, qkv, nullptr);

    flash2<<<dim3(S_ / 128, NH_, B_), 256, 0, stream>>>(
        qkv, qkv + (size_t)MTOT * H_, qkv + (size_t)2 * MTOT * H_, xb);

    gemm_m97<1><<<dim3(32, 8), 256, 0, stream>>>(xb, Wo, nullptr, nullptr, nullptr, out);
}

// Round 4
// 150.513 us; speedup vs baseline: 2.5144x; 1.4972x over previous
//
#include <hip/hip_runtime.h>
#include <hip/hip_bf16.h>

#define B_   2
#define S_   2048
#define H_   1024
#define NH_  16
#define HD_  64
#define MTOT 4096
#define KD   1024

typedef __attribute__((ext_vector_type(4)))  float    f32x4;
typedef __attribute__((ext_vector_type(16))) float    f32x16;
typedef __attribute__((ext_vector_type(8)))  short    bf16x8;
typedef __attribute__((ext_vector_type(2)))  unsigned u32x2;
typedef __attribute__((ext_vector_type(4)))  unsigned u32x4;

// f32 -> bf16 RNE (exact bit-math; used in BW-bound converters)
__device__ inline short f2bf(float x) {
    union { float f; unsigned u; } v; v.f = x;
    unsigned r = v.u + 0x7fffu + ((v.u >> 16) & 1u);
    return (short)(r >> 16);
}
__device__ inline unsigned pk2(float lo, float hi) {
    return (unsigned)(unsigned short)f2bf(lo) | ((unsigned)(unsigned short)f2bf(hi) << 16);
}
// HW pack: 2 f32 -> u32 of 2 bf16 (1 VALU op; used in compute-bound loops)
__device__ inline unsigned cvtpk(float lo, float hi) {
    unsigned r;
    asm("v_cvt_pk_bf16_f32 %0, %1, %2" : "=v"(r) : "v"(lo), "v"(hi));
    return r;
}
// async global->LDS, 16B/lane; LDS dest wave-uniform base + lane*16
__device__ inline void gload16(const void* g, void* l) {
    __builtin_amdgcn_global_load_lds(
        (const __attribute__((address_space(1))) unsigned*)g,
        (__attribute__((address_space(3))) unsigned*)l, 16, 0, 0);
}

// ---------------------------------------------------------------------------
// x (f32) -> bf16, 8 elems/thread
// ---------------------------------------------------------------------------
__global__ __launch_bounds__(256) void cvt_x(const float* __restrict__ x,
                                             unsigned* __restrict__ xb) {
    const size_t i = ((size_t)blockIdx.x * 256 + threadIdx.x) * 8;
    const f32x4 a = *(const f32x4*)(x + i);
    const f32x4 b = *(const f32x4*)(x + i + 4);
    u32x4 p;
    p[0] = pk2(a[0], a[1]); p[1] = pk2(a[2], a[3]);
    p[2] = pk2(b[0], b[1]); p[3] = pk2(b[2], b[3]);
    *(u32x4*)(xb + i / 2) = p;
}

// weights (4x [1024x1024] f32) -> bf16, blockIdx.y selects matrix
__global__ __launch_bounds__(256) void wcvt(const float* __restrict__ W0,
                                            const float* __restrict__ W1,
                                            const float* __restrict__ W2,
                                            const float* __restrict__ W3,
                                            unsigned* __restrict__ wb) {
    const float* W = (blockIdx.y == 0) ? W0 : (blockIdx.y == 1) ? W1
                   : (blockIdx.y == 2) ? W2 : W3;
    const size_t i = ((size_t)blockIdx.x * 256 + threadIdx.x) * 8;
    const f32x4 a = *(const f32x4*)(W + i);
    const f32x4 b = *(const f32x4*)(W + i + 4);
    u32x4 p;
    p[0] = pk2(a[0], a[1]); p[1] = pk2(a[2], a[3]);
    p[2] = pk2(b[0], b[1]); p[3] = pk2(b[2], b[3]);
    *(u32x4*)(wb + (size_t)blockIdx.y * (H_ * KD / 2) + i / 2) = p;
}

// ---------------------------------------------------------------------------
// GEMM  C[m][n] = sum_k A[m][k] * W[n][k],  A and W both bf16.
// Both tiles staged via global_load_lds w=16, XOR-swizzled.
// MODE 0: fused QKV (blockIdx.y -> weight + n-panel), bf16 head-layout out,
//         LDS-transpose epilogue for coalesced stores.
// MODE 1: final projection, f32 row-major out.
// 128x128 tile, BK=64, 256 threads (2x2 waves, 64x64 each).
// ---------------------------------------------------------------------------
template <int MODE>
__global__ __launch_bounds__(256) void gemm_m97(const short* __restrict__ A,
                                                const short* __restrict__ Wb,
                                                short* __restrict__ outb,
                                                float* __restrict__ outf) {
    __shared__ short Sm[128 * 128];          // staging: As=Sm[0:8192), Bs=Sm[8192:16384)
    short* As = Sm;
    short* Bs = Sm + 8192;

    const int tid = threadIdx.x, wave = tid >> 6, lane = tid & 63;
    const int wm = (wave >> 1) * 64, wn = (wave & 1) * 64;
    const int m0 = blockIdx.x * 128;

    int n0, widx;
    if constexpr (MODE == 0) {
        widx = blockIdx.y >> 3;
        n0 = (blockIdx.y & 7) * 128;
    } else {
        widx = 0;
        n0 = blockIdx.y * 128;
    }
    const short* W = Wb + (size_t)widx * H_ * KD;

    f32x4 acc[4][4] = {};

    for (int k0 = 0; k0 < KD; k0 += 64) {
#pragma unroll
        for (int c = 0; c < 4; ++c) {
            const int lin = wave * 4096 + c * 1024 + lane * 16;   // byte in tile
            const int row = lin >> 7;
            const int col = (lin & 127) ^ ((row & 7) << 4);
            gload16(A + (size_t)(m0 + row) * KD + k0 + (col >> 1),
                    (char*)As + wave * 4096 + c * 1024);
            gload16(W + (size_t)(n0 + row) * KD + k0 + (col >> 1),
                    (char*)Bs + wave * 4096 + c * 1024);
        }
        __syncthreads();

#pragma unroll
        for (int ks = 0; ks < 2; ++ks) {
            bf16x8 af[4], bf[4];
#pragma unroll
            for (int i = 0; i < 4; ++i) {
                const int row = wm + i * 16 + (lane & 15);
                af[i] = *(const bf16x8*)((char*)As + row * 128 +
                        ((ks * 64 + (lane >> 4) * 16) ^ ((row & 7) << 4)));
            }
#pragma unroll
            for (int j = 0; j < 4; ++j) {
                const int row = wn + j * 16 + (lane & 15);
                bf[j] = *(const bf16x8*)((char*)Bs + row * 128 +
                        ((ks * 64 + (lane >> 4) * 16) ^ ((row & 7) << 4)));
            }
#pragma unroll
            for (int i = 0; i < 4; ++i)
#pragma unroll
                for (int j = 0; j < 4; ++j)
                    acc[i][j] = __builtin_amdgcn_mfma_f32_16x16x32_bf16(af[i], bf[j], acc[i][j], 0, 0, 0);
        }
        __syncthreads();
    }

    if constexpr (MODE == 0) {
        // bf16 -> swizzled LDS [128][128] -> coalesced head-layout stores
#pragma unroll
        for (int i = 0; i < 4; ++i)
#pragma unroll
            for (int j = 0; j < 4; ++j)
#pragma unroll
                for (int r = 0; r < 4; ++r) {
                    const int mi = wm + i * 16 + (lane >> 4) * 4 + r;
                    const int ni = wn + j * 16 + (lane & 15);
                    const int byt = (mi * 256 + ni * 2) ^ ((mi & 7) << 4);
                    *(short*)((char*)Sm + byt) = f2bf(acc[i][j][r]);
                }
        __syncthreads();
        const int row = tid >> 1, half = tid & 1;
        const int m = m0 + row, bb = m >> 11, s = m & 2047;
        const int hh = (n0 >> 6) + half;
        short* dst = outb + (size_t)widx * MTOT * H_ +
                     (((size_t)(bb * NH_ + hh)) * S_ + s) * HD_;
#pragma unroll
        for (int k = 0; k < 8; ++k) {
            const int byt = (row * 256 + half * 128 + k * 16) ^ ((row & 7) << 4);
            *(bf16x8*)(dst + k * 8) = *(const bf16x8*)((char*)Sm + byt);
        }
    } else {
#pragma unroll
        for (int i = 0; i < 4; ++i)
#pragma unroll
            for (int j = 0; j < 4; ++j)
#pragma unroll
                for (int r = 0; r < 4; ++r) {
                    const int m = m0 + wm + i * 16 + (lane >> 4) * 4 + r;
                    const int n = n0 + wn + j * 16 + (lane & 15);
                    outf[(size_t)m * H_ + n] = acc[i][j][r];
                }
    }
}

// ---------------------------------------------------------------------------
// Flash attention, causal, swapped-operand 32x32 MFMA.
// grid = 512 linear; decode pairs (qt=t,b=0) with (qt=15-t,b=1) so blocks
// bx and bx+256 (same CU under XCD round-robin) sum to constant work.
// 256 threads = 4 waves x 32 q-rows. KV tile = 64.
// ---------------------------------------------------------------------------
__global__ __launch_bounds__(256) void flash2(const short* __restrict__ Qb,
                                              const short* __restrict__ Kb,
                                              const short* __restrict__ Vb,
                                              short* __restrict__ Ob) {
    const int bx = blockIdx.x;
    const int hi = bx >> 8, u = bx & 255;
    const int h = u >> 4, tq = u & 15;
    const int qt = hi ? (15 - tq) : tq;
    const int b  = hi;

    const int tid = threadIdx.x, wave = tid >> 6, lane = tid & 63;
    const int q0 = qt * 128;
    const int qw0 = q0 + wave * 32;
    const size_t hoff = ((size_t)(b * NH_ + h)) * S_ * HD_;
    const short* Q = Qb + hoff;
    const short* K = Kb + hoff;
    const short* V = Vb + hoff;

    __shared__ short Ks[64 * 64];   // [key][d], XOR-swizzled
    __shared__ short Vt[64 * 64];   // [d][key], XOR-swizzled

    const int ql = lane & 31;       // q column owned by this lane
    const int hh = lane >> 5;

    bf16x8 qf[4];
#pragma unroll
    for (int ds = 0; ds < 4; ++ds)
        qf[ds] = *(const bf16x8*)(Q + (size_t)(qw0 + ql) * HD_ + ds * 16 + hh * 8);

    f32x16 ot[2] = {};
    float mrun = -1e30f, lrun = 0.f;
    const float c2 = 0.18033688011112042f;   // 0.125 * log2(e)

    const int nkt = 2 * qt + 2;
    for (int kt = 0; kt < nkt; ++kt) {
        __syncthreads();
#pragma unroll
        for (int c = 0; c < 2; ++c) {
            const int lin = wave * 2048 + c * 1024 + lane * 16;
            const int row = lin >> 7;
            const int col = (lin & 127) ^ ((row & 7) << 4);
            gload16(K + (size_t)(kt * 64 + row) * HD_ + (col >> 1),
                    (char*)Ks + wave * 2048 + c * 1024);
        }
        {
            const int kk = (tid & 31) * 2, d0 = (tid >> 5) * 8;
            const bf16x8 v0 = *(const bf16x8*)(V + (size_t)(kt * 64 + kk) * HD_ + d0);
            const bf16x8 v1 = *(const bf16x8*)(V + (size_t)(kt * 64 + kk + 1) * HD_ + d0);
#pragma unroll
            for (int i = 0; i < 8; ++i) {
                const int d = d0 + i;
                const int byt = d * 128 + kk * 2;
                *(unsigned*)((char*)Vt + (byt ^ ((d & 7) << 4))) =
                    (unsigned)(unsigned short)v0[i] | ((unsigned)(unsigned short)v1[i] << 16);
            }
        }
        __syncthreads();

        if (kt * 64 <= qw0 + 31) {
            const bool need_mask = (kt * 64 + 63) > qw0;

            f32x16 st[2] = {};
#pragma unroll
            for (int t = 0; t < 2; ++t)
#pragma unroll
                for (int ds = 0; ds < 4; ++ds) {
                    const int row = t * 32 + ql;
                    const bf16x8 kf = *(const bf16x8*)((char*)Ks + row * 128 +
                            ((ds * 32 + hh * 16) ^ ((row & 7) << 4)));
                    st[t] = __builtin_amdgcn_mfma_f32_32x32x16_bf16(kf, qf[ds], st[t], 0, 0, 0);
                }

            float sraw[32];
#pragma unroll
            for (int t = 0; t < 2; ++t)
#pragma unroll
                for (int r = 0; r < 16; ++r) {
                    float v = st[t][r];
                    if (need_mask) {
                        const int key = kt * 64 + t * 32 + (r & 3) + 8 * (r >> 2) + 4 * hh;
                        if (key > qw0 + ql) v = -1e30f;
                    }
                    sraw[t * 16 + r] = v;
                }

            // tile max (tree + 1 shfl)
            float tr[16];
#pragma unroll
            for (int i = 0; i < 16; ++i) tr[i] = fmaxf(sraw[i], sraw[i + 16]);
#pragma unroll
            for (int stp = 8; stp >= 1; stp >>= 1)
#pragma unroll
                for (int i = 0; i < 8; ++i)
                    if (i < stp) tr[i] = fmaxf(tr[i], tr[i + stp]);
            const float pmax = fmaxf(tr[0], __shfl_xor(tr[0], 32, 64));

            // defer-max: rescale only when the running max grew materially
            if (!__all((pmax - mrun) <= 44.36f)) {
                const float mnew = fmaxf(mrun, pmax);
                const float corr = exp2f((mrun - mnew) * c2);
                mrun = mnew;
                lrun *= corr;
#pragma unroll
                for (int dt = 0; dt < 2; ++dt)
#pragma unroll
                    for (int r = 0; r < 16; ++r) ot[dt][r] *= corr;
            }
            const float mc = mrun * c2;

            float p[32];
#pragma unroll
            for (int i = 0; i < 32; ++i) p[i] = exp2f(fmaf(sraw[i], c2, -mc));
            float ts[16];
#pragma unroll
            for (int i = 0; i < 16; ++i) ts[i] = p[i] + p[i + 16];
#pragma unroll
            for (int stp = 8; stp >= 1; stp >>= 1)
#pragma unroll
                for (int i = 0; i < 8; ++i)
                    if (i < stp) ts[i] += ts[i + stp];
            lrun += ts[0] + __shfl_xor(ts[0], 32, 64);

            // P pack (HW cvt_pk) -> B-frag, PV MFMAs
#pragma unroll
            for (int ks = 0; ks < 4; ++ks) {
                const int t = ks >> 1, rb = (ks & 1) * 8;
                const unsigned a0 = cvtpk(p[t * 16 + rb + 0], p[t * 16 + rb + 1]);
                const unsigned a1 = cvtpk(p[t * 16 + rb + 2], p[t * 16 + rb + 3]);
                const unsigned a2 = cvtpk(p[t * 16 + rb + 4], p[t * 16 + rb + 5]);
                const unsigned a3 = cvtpk(p[t * 16 + rb + 6], p[t * 16 + rb + 7]);
                const unsigned s0 = __shfl_xor(a0, 32, 64);
                const unsigned s1 = __shfl_xor(a1, 32, 64);
                const unsigned s2 = __shfl_xor(a2, 32, 64);
                const unsigned s3 = __shfl_xor(a3, 32, 64);
                u32x4 pw;
                pw[0] = hh ? s2 : a0;
                pw[1] = hh ? s3 : a1;
                pw[2] = hh ? a2 : s0;
                pw[3] = hh ? a3 : s1;
                const bf16x8 pf = __builtin_bit_cast(bf16x8, pw);
#pragma unroll
                for (int dt = 0; dt < 2; ++dt) {
                    const int row = dt * 32 + ql;
                    const bf16x8 vf = *(const bf16x8*)((char*)Vt + row * 128 +
                            ((ks * 32 + hh * 16) ^ ((row & 7) << 4)));
                    ot[dt] = __builtin_amdgcn_mfma_f32_32x32x16_bf16(vf, pf, ot[dt], 0, 0, 0);
                }
            }
        }
    }

    // epilogue: O^T regs -> row-major bf16 [B*S][H], paired cvt_pk + 8B stores
    const float inv = 1.f / lrun;
    short* orow = Ob + ((size_t)(b * S_) + q0 + wave * 32 + ql) * H_ + h * HD_;
#pragma unroll
    for (int dt = 0; dt < 2; ++dt)
#pragma unroll
        for (int g4 = 0; g4 < 4; ++g4) {
            const int dbase = dt * 32 + 8 * g4 + 4 * hh;
            u32x2 w;
            w[0] = cvtpk(ot[dt][g4 * 4 + 0] * inv, ot[dt][g4 * 4 + 1] * inv);
            w[1] = cvtpk(ot[dt][g4 * 4 + 2] * inv, ot[dt][g4 * 4 + 3] * inv);
            *(u32x2*)(orow + dbase) = w;
        }
}

// ---------------------------------------------------------------------------
extern "C" void kernel_launch(void* const* d_in, const int* in_sizes, int n_in,
                              void* d_out, int out_size, void* d_ws, size_t ws_size,
                              hipStream_t stream) {
    const float* x  = (const float*)d_in[0];
    const float* Wq = (const float*)d_in[2];
    const float* Wk = (const float*)d_in[3];
    const float* Wv = (const float*)d_in[4];
    const float* Wo = (const float*)d_in[5];
    float* out = (float*)d_out;

    short* qkv = (short*)d_ws;                        // 3 x 4M bf16
    short* xb  = qkv + (size_t)3 * MTOT * H_;         // 4M bf16 (x, then attn-out)
    short* wb  = xb + (size_t)MTOT * H_;              // 4 x 1M bf16 weights

    cvt_x<<<2048, 256, 0, stream>>>(x, (unsigned*)xb);
    wcvt<<<dim3(512, 4), 256, 0, stream>>>(Wq, Wk, Wv, Wo, (unsigned*)wb);

    gemm_m97<0><<<dim3(32, 24), 256, 0, stream>>>(xb, wb, qkv, nullptr);

    flash2<<<dim3(512), 256, 0, stream>>>(
        qkv, qkv + (size_t)MTOT * H_, qkv + (size_t)2 * MTOT * H_, xb);

    gemm_m97<1><<<dim3(32, 8), 256, 0, stream>>>(
        xb, wb + (size_t)3 * H_ * KD, nullptr, out);
}